// Round 3
// baseline (107.788 us; speedup 1.0000x reference)
//
#include <hip/hip_runtime.h>

// x[B=32, C=512, H=256, W=14] f32. Per-(b,h) shuffle of the 7 same-parity
// columns (p = h%2): out[b,c,h,2j+p] = x[b,c,h,2*perm[b,h,j]+p]; other
// columns identity. Pure within-row (56 B) gather, broadcast over C.
//
// Round 3: async global->LDS staging (global_load_lds width=16, no VGPR
// round trip) + perms read directly from global (L1-resident 7 KB slice)
// so LDS = 28 KB -> 5 blocks/CU (20 waves) instead of 4 (16 waves).
//
//   row = flat/14; h = row & 255; b = row >> 17 (C*H = 2^17).
//   TILE = 512 consecutive rows = 7168 floats = 1792 float4 per block.
//   b is constant per tile (512 | 2^17), h cycles 0..255 twice.

#define TILE_ROWS   512
#define TILE_FLOATS (TILE_ROWS * 14)        // 7168
#define TILE_VEC4   (TILE_FLOATS / 4)       // 1792 = 7 * 256

#define GLOAD_LDS16(gp, lp)                                                   \
    __builtin_amdgcn_global_load_lds(                                         \
        (const __attribute__((address_space(1))) void*)(gp),                  \
        (__attribute__((address_space(3))) void*)(lp), 16, 0, 0)

__global__ __launch_bounds__(256, 5) void GSRS_shuffle_lds_kernel(
    const float* __restrict__ x,
    const int* __restrict__ perms,
    float* __restrict__ out)
{
    __shared__ float tile[TILE_FLOATS];     // 28 KB

    const unsigned tid  = threadIdx.x;
    const unsigned tb   = blockIdx.x;       // tile index, 0..8191
    const unsigned base = tb * TILE_FLOATS; // float offset of tile
    const unsigned row0 = tb * TILE_ROWS;
    const unsigned b    = row0 >> 17;       // batch, constant per tile

    // Stage x tile: 1792 float4 via direct HBM->LDS DMA.
    // Layout is linear: lds byte addr = (i*256 + tid)*16 = wave-uniform
    // base + lane*16, exactly the HW-required form.
    const float4* xv = reinterpret_cast<const float4*>(x + base);
    float4*       tv = reinterpret_cast<float4*>(tile);
#pragma unroll
    for (int i = 0; i < 7; ++i)
        GLOAD_LDS16(xv + i * 256 + tid, tv + i * 256 + tid);

    __syncthreads();   // drains vmcnt(0): LDS tile complete

    // Gather from LDS, store coalesced float4. Perms from global (L1-hot).
    const int* __restrict__ pslice = perms + b * (256u * 7u);
    float4* ov = reinterpret_cast<float4*>(out + base);
#pragma unroll
    for (int i = 0; i < 7; ++i) {
        const unsigned q  = i * 256 + tid;  // float4 index within tile
        unsigned lo   = q * 4u;             // float offset within tile
        unsigned lrow = lo / 14u;           // local row
        unsigned w    = lo - lrow * 14u;
        float v[4];
#pragma unroll
        for (int k = 0; k < 4; ++k) {
            const unsigned h = lrow & 255u; // (row0 + lrow) & 255 == lrow & 255
            const unsigned p = h & 1u;
            unsigned src;
            if ((w & 1u) == p)
                src = 2u * (unsigned)pslice[h * 7u + (w >> 1)] + p;
            else
                src = w;
            v[k] = tile[lrow * 14u + src];
            if (++w == 14u) { w = 0u; ++lrow; }
        }
        ov[q] = make_float4(v[0], v[1], v[2], v[3]);
    }
}

extern "C" void kernel_launch(void* const* d_in, const int* in_sizes, int n_in,
                              void* d_out, int out_size, void* d_ws, size_t ws_size,
                              hipStream_t stream) {
    const float* x     = (const float*)d_in[0];
    const int*   perms = (const int*)d_in[1];
    float*       out   = (float*)d_out;

    // 4,194,304 rows / 512 rows per tile = 8192 tiles, one block each.
    hipLaunchKernelGGL(GSRS_shuffle_lds_kernel, dim3(8192), dim3(256), 0, stream,
                       x, perms, out);
}

// Round 4
// 86.696 us; speedup vs baseline: 1.2433x; 1.2433x over previous
//
#include <hip/hip_runtime.h>

// x[B=32, C=512, H=256, W=14] f32. Per-(b,h) shuffle of the 7 same-parity
// columns (p = h%2): out[b,c,h,2j+p] = x[b,c,h,2*perm[b,h,j]+p]; other
// columns identity. Pure within-row (56 B) gather, broadcast over C.
//
// Round 4: wave-private tiles, no __syncthreads.
//  - Block stages 512 rows (28 KB) via global_load_lds width=16 (HBM->LDS DMA).
//  - Each wave owns a 128-row slice (448 float4) + builds its cmap slice.
//  - cmap[h][w] = source column byte, [256][16] = 4 KB; branch-free gather.
//  - LDS = 32 KB exactly -> 5 blocks/CU, 20 waves/CU.
//  - Sync = one wave-local s_waitcnt vmcnt(0) lgkmcnt(0).
//
//   row = flat/14; h = row & 255; b = row >> 17 (C*H = 2^17).
//   Tile row0 = blockIdx.x*512 (multiple of 512 => row0 & 255 == 0).

#define TILE_ROWS   512
#define TILE_FLOATS (TILE_ROWS * 14)   // 7168 floats = 28672 B
#define WAVE_ROWS   128
#define WAVE_VEC4   448                // 128*14/4 float4 per wave

#define GLOAD_LDS16(gp, lp)                                                   \
    __builtin_amdgcn_global_load_lds(                                         \
        (const __attribute__((address_space(1))) void*)(gp),                  \
        (__attribute__((address_space(3))) void*)(lp), 16, 0, 0)

__global__ __launch_bounds__(256, 5) void GSRS_shuffle_wave_kernel(
    const float* __restrict__ x,
    const int* __restrict__ perms,
    float* __restrict__ out)
{
    __shared__ float tile[TILE_FLOATS];        // 28672 B
    __shared__ unsigned char cmap[256][16];    // 4096 B  (total 32768 B)

    const unsigned tid  = threadIdx.x;
    const unsigned lane = tid & 63u;
    const unsigned wv   = tid >> 6;            // wave id 0..3
    const unsigned tb   = blockIdx.x;          // tile index, 0..8191
    const unsigned base = tb * TILE_FLOATS;    // float offset of tile
    const unsigned row0 = tb * TILE_ROWS;
    const unsigned b    = row0 >> 17;          // batch, constant per tile

    // ---- stage x subtile: 7 x global_load_lds (16 B), wave-uniform base +
    // lane*16 LDS layout (linear), per-lane global source. Issue first so
    // HBM latency hides under the cmap build below.
    const float4* xv = reinterpret_cast<const float4*>(x + base);
    float4*       tv = reinterpret_cast<float4*>(tile);
    const unsigned q0 = wv * WAVE_VEC4 + lane;
#pragma unroll
    for (int i = 0; i < 7; ++i)
        GLOAD_LDS16(xv + q0 + i * 64, tv + q0 + i * 64);

    // ---- wave-private cmap build: lane owns tile-rows r0, r0+1 of its
    // wave's 128-row slice. h = row & 255; waves 0/2 (and 1/3) write
    // identical bytes to the same entries (same b, same h) - benign.
    {
        const unsigned r0 = wv * WAVE_ROWS + 2u * lane;   // even, 0..510
        const unsigned h0 = r0 & 255u;                    // even
        const int* pr = perms + b * 1792u + h0 * 7u;      // 14 consecutive ints
        int pm[14];
#pragma unroll
        for (int j = 0; j < 14; ++j) pm[j] = pr[j];
#pragma unroll
        for (int r = 0; r < 2; ++r) {
            const unsigned h = h0 + r;
            const unsigned p = h & 1u;
            union { unsigned char c[16]; uint4 v; } u;
#pragma unroll
            for (int w14 = 0; w14 < 14; ++w14) {
                unsigned src;
                if (((unsigned)w14 & 1u) == p)
                    src = 2u * (unsigned)pm[r * 7 + (w14 >> 1)] + p;
                else
                    src = (unsigned)w14;
                u.c[w14] = (unsigned char)src;
            }
            u.c[14] = 0; u.c[15] = 0;
            *reinterpret_cast<uint4*>(&cmap[h][0]) = u.v;  // ds_write_b128
        }
    }

    // ---- wave-local drain: own DMA into LDS (vmcnt) + own cmap writes
    // (lgkmcnt). No __syncthreads: all data below is wave-private.
    asm volatile("s_waitcnt vmcnt(0) lgkmcnt(0)" ::: "memory");

    // ---- branch-free gather from LDS, coalesced float4 store.
    float4* ov = reinterpret_cast<float4*>(out + base);
#pragma unroll
    for (int i = 0; i < 7; ++i) {
        const unsigned q  = q0 + i * 64;       // float4 index within tile
        unsigned lo   = q * 4u;                // float offset within tile
        unsigned lrow = lo / 14u;              // local row (wave's 128-row slice)
        unsigned w14  = lo - lrow * 14u;
        float v[4];
#pragma unroll
        for (int k4 = 0; k4 < 4; ++k4) {
            const unsigned h   = lrow & 255u;
            const unsigned src = cmap[h][w14]; // ds_read_u8
            v[k4] = tile[lrow * 14u + src];    // ds_read_b32
            if (++w14 == 14u) { w14 = 0u; ++lrow; }
        }
        ov[q] = make_float4(v[0], v[1], v[2], v[3]);
    }
}

extern "C" void kernel_launch(void* const* d_in, const int* in_sizes, int n_in,
                              void* d_out, int out_size, void* d_ws, size_t ws_size,
                              hipStream_t stream) {
    const float* x     = (const float*)d_in[0];
    const int*   perms = (const int*)d_in[1];
    float*       out   = (float*)d_out;

    // 4,194,304 rows / 512 rows per tile = 8192 tiles, one block each.
    hipLaunchKernelGGL(GSRS_shuffle_wave_kernel, dim3(8192), dim3(256), 0, stream,
                       x, perms, out);
}